// Round 1
// baseline (17654.234 us; speedup 1.0000x reference)
//
#include <hip/hip_runtime.h>
#include <math.h>

static constexpr int BATCH = 512;
static constexpr int F = 128;
static constexpr int NEMB = 64;
static constexpr int H = 8;
static constexpr int GH = 32;         // per-head hidden
static constexpr int NIN2 = H * GH;   // 256
static constexpr int MH = 256;        // MLP hidden
static constexpr float ALPHA = 0.2f;
static constexpr float NEGV = -9e15f;

// ---------------- kernel A: x[b][f][:] = emb[ids[b][f]] * vals[b][f] ----------------
__global__ __launch_bounds__(256) void k_embed(
    const int* __restrict__ ids, const float* __restrict__ vals,
    const float* __restrict__ emb, float* __restrict__ x)
{
  int idx = blockIdx.x * 256 + threadIdx.x;       // float4 index; total B*F*16
  int e4 = idx & 15;
  int bf = idx >> 4;
  int id = ids[bf];
  float v = vals[bf];
  float4 r = reinterpret_cast<const float4*>(emb)[(size_t)id * 16 + e4];
  r.x *= v; r.y *= v; r.z *= v; r.w *= v;
  reinterpret_cast<float4*>(x)[idx] = r;
}

// ---------------- kernel B: one GAT layer, one block per (b, head) ----------------
// hin [B][F][NIN] -> hout[b][f][h*GH + o] = elu( softmax_j( lrelu(si+sj)*mask ) @ hW )
template <int NIN>
__global__ __launch_bounds__(256, 2) void k_gat(
    const float* __restrict__ hin,
    const float* __restrict__ Wg,    // [H][NIN][GH]
    const float* __restrict__ ag,    // [H][2*GH]
    const float* __restrict__ adj,   // [F][F]
    float* __restrict__ hout)        // [B][F][NIN2]
{
  const int b = blockIdx.x >> 3;
  const int h = blockIdx.x & 7;
  const int t = threadIdx.x;

  __shared__ float Wl[NIN * GH];     // [i][o] row-major
  __shared__ float hW[F * 36];       // [f][o] stride 36 (16B-aligned rows)
  __shared__ float sil[F];
  __shared__ float sjl[F];
  __shared__ float al[2 * GH];

  {
    const float4* src = reinterpret_cast<const float4*>(Wg + (size_t)h * NIN * GH);
    float4* dst = reinterpret_cast<float4*>(Wl);
    for (int i = t; i < NIN * GH / 4; i += 256) dst[i] = src[i];
    if (t < 2 * GH) al[t] = ag[h * 2 * GH + t];
  }
  __syncthreads();

  // ---- phase 1: hW[f][o] = sum_i hin[b][f][i] * Wl[i][o]  (4 rows x 4 cols / thread)
  const int fg = t >> 3;             // 0..31
  const int og = t & 7;              // 0..7
  const int f0 = fg * 4;
  float acc[4][4];
#pragma unroll
  for (int r = 0; r < 4; r++)
#pragma unroll
    for (int c = 0; c < 4; c++) acc[r][c] = 0.f;

  const float* hb = hin + ((size_t)b * F + f0) * NIN;
  for (int i = 0; i < NIN; i += 4) {
    float4 hv0 = *reinterpret_cast<const float4*>(hb + 0 * NIN + i);
    float4 hv1 = *reinterpret_cast<const float4*>(hb + 1 * NIN + i);
    float4 hv2 = *reinterpret_cast<const float4*>(hb + 2 * NIN + i);
    float4 hv3 = *reinterpret_cast<const float4*>(hb + 3 * NIN + i);
    float hs[4][4];
    hs[0][0] = hv0.x; hs[0][1] = hv0.y; hs[0][2] = hv0.z; hs[0][3] = hv0.w;
    hs[1][0] = hv1.x; hs[1][1] = hv1.y; hs[1][2] = hv1.z; hs[1][3] = hv1.w;
    hs[2][0] = hv2.x; hs[2][1] = hv2.y; hs[2][2] = hv2.z; hs[2][3] = hv2.w;
    hs[3][0] = hv3.x; hs[3][1] = hv3.y; hs[3][2] = hv3.z; hs[3][3] = hv3.w;
#pragma unroll
    for (int d = 0; d < 4; d++) {
      float4 wv = reinterpret_cast<const float4*>(Wl)[(i + d) * (GH / 4) + og];
#pragma unroll
      for (int r = 0; r < 4; r++) {
        acc[r][0] += hs[r][d] * wv.x;
        acc[r][1] += hs[r][d] * wv.y;
        acc[r][2] += hs[r][d] * wv.z;
        acc[r][3] += hs[r][d] * wv.w;
      }
    }
  }

  // store hW tile + per-row si/sj partials (reduce over the 8 og lanes)
#pragma unroll
  for (int r = 0; r < 4; r++) {
    *reinterpret_cast<float4*>(&hW[(f0 + r) * 36 + og * 4]) =
        make_float4(acc[r][0], acc[r][1], acc[r][2], acc[r][3]);
    float sip = acc[r][0] * al[og * 4 + 0] + acc[r][1] * al[og * 4 + 1]
              + acc[r][2] * al[og * 4 + 2] + acc[r][3] * al[og * 4 + 3];
    float sjp = acc[r][0] * al[GH + og * 4 + 0] + acc[r][1] * al[GH + og * 4 + 1]
              + acc[r][2] * al[GH + og * 4 + 2] + acc[r][3] * al[GH + og * 4 + 3];
    sip += __shfl_xor(sip, 1); sip += __shfl_xor(sip, 2); sip += __shfl_xor(sip, 4);
    sjp += __shfl_xor(sjp, 1); sjp += __shfl_xor(sjp, 2); sjp += __shfl_xor(sjp, 4);
    if (og == 0) { sil[f0 + r] = sip; sjl[f0 + r] = sjp; }
  }
  __syncthreads();

  // ---- phase 2: attention + PV. thread -> rows {ip, ip+64}, quad-lane l covers j = 4*jj + l
  const int ip = t >> 2;
  const int l = t & 3;
  const float siA = sil[ip];
  const float siB = sil[ip + 64];

  float sA[32], sB[32];
#pragma unroll
  for (int jj = 0; jj < 32; jj++) {
    int j = jj * 4 + l;
    float sjv = sjl[j];
    float mA = adj[ip * F + j];
    float mB = adj[(ip + 64) * F + j];
    mA = mA > 0.f ? mA : NEGV;
    mB = mB > 0.f ? mB : NEGV;
    float eA = siA + sjv; eA = eA > 0.f ? eA : ALPHA * eA;
    float eB = siB + sjv; eB = eB > 0.f ? eB : ALPHA * eB;
    sA[jj] = eA * mA;
    sB[jj] = eB * mB;
  }
  float mxA = sA[0], mxB = sB[0];
#pragma unroll
  for (int jj = 1; jj < 32; jj++) { mxA = fmaxf(mxA, sA[jj]); mxB = fmaxf(mxB, sB[jj]); }
  mxA = fmaxf(mxA, __shfl_xor(mxA, 1)); mxA = fmaxf(mxA, __shfl_xor(mxA, 2));
  mxB = fmaxf(mxB, __shfl_xor(mxB, 1)); mxB = fmaxf(mxB, __shfl_xor(mxB, 2));
  float smA = 0.f, smB = 0.f;
#pragma unroll
  for (int jj = 0; jj < 32; jj++) {
    sA[jj] = __expf(sA[jj] - mxA); smA += sA[jj];
    sB[jj] = __expf(sB[jj] - mxB); smB += sB[jj];
  }
  smA += __shfl_xor(smA, 1); smA += __shfl_xor(smA, 2);
  smB += __shfl_xor(smB, 1); smB += __shfl_xor(smB, 2);
  const float invA = 1.f / smA;
  const float invB = 1.f / smB;

  // PV: lane owns o-slice [l*8, l*8+8); probabilities circulate via quad shuffles.
  const int lo = l * 8;
  float oA8[8], oB8[8];
#pragma unroll
  for (int k = 0; k < 8; k++) { oA8[k] = 0.f; oB8[k] = 0.f; }
#pragma unroll
  for (int jj = 0; jj < 32; jj++) {
#pragma unroll
    for (int r = 0; r < 4; r++) {
      float pA = (r == 0) ? sA[jj] : __shfl_xor(sA[jj], r);
      float pB = (r == 0) ? sB[jj] : __shfl_xor(sB[jj], r);
      int j = jj * 4 + (l ^ r);
      float4 w0 = *reinterpret_cast<const float4*>(&hW[j * 36 + lo]);
      float4 w1 = *reinterpret_cast<const float4*>(&hW[j * 36 + lo + 4]);
      oA8[0] += pA * w0.x; oA8[1] += pA * w0.y; oA8[2] += pA * w0.z; oA8[3] += pA * w0.w;
      oA8[4] += pA * w1.x; oA8[5] += pA * w1.y; oA8[6] += pA * w1.z; oA8[7] += pA * w1.w;
      oB8[0] += pB * w0.x; oB8[1] += pB * w0.y; oB8[2] += pB * w0.z; oB8[3] += pB * w0.w;
      oB8[4] += pB * w1.x; oB8[5] += pB * w1.y; oB8[6] += pB * w1.z; oB8[7] += pB * w1.w;
    }
  }

  float* pAp = hout + ((size_t)b * F + ip) * NIN2 + h * GH + lo;
  float* pBp = hout + ((size_t)b * F + ip + 64) * NIN2 + h * GH + lo;
#pragma unroll
  for (int q = 0; q < 2; q++) {
    float4 vA, vB;
    float* a4 = &vA.x;
    float* b4 = &vB.x;
#pragma unroll
    for (int c = 0; c < 4; c++) {
      float xA = oA8[q * 4 + c] * invA; a4[c] = xA > 0.f ? xA : expm1f(xA);
      float xB = oB8[q * 4 + c] * invB; b4[c] = xB > 0.f ? xB : expm1f(xB);
    }
    reinterpret_cast<float4*>(pAp)[q] = vA;
    reinterpret_cast<float4*>(pBp)[q] = vB;
  }
}

// ---------------- kernel C: MLP layer 1, K-split partial GEMM ----------------
// A = h2 [512][32768], Bw = w0 [32768][256]; part[kc][512][256] partial sums
__global__ __launch_bounds__(256, 4) void k_mlp1(
    const float* __restrict__ A, const float* __restrict__ Bw,
    float* __restrict__ part)
{
  const int kc = blockIdx.x;       // 0..31  (K chunk of 1024)
  const int rt = blockIdx.y;       // 0..7   (row tile of 64)
  const int t = threadIdx.x;
  __shared__ float At[64 * 68];

  const int r0 = rt * 64;
  const int k0 = kc * 1024;
  const int o = t & 127;           // cols {o, o+128}
  const int rh = t >> 7;           // row half (32 rows)

  float acc0[32], acc1[32];
#pragma unroll
  for (int r = 0; r < 32; r++) { acc0[r] = 0.f; acc1[r] = 0.f; }

  for (int kt = 0; kt < 16; kt++) {
#pragma unroll
    for (int it = 0; it < 4; it++) {
      int f4 = it * 256 + t;                 // 0..1023
      int rr = f4 >> 4;
      int cc = (f4 & 15) * 4;
      float4 v = *reinterpret_cast<const float4*>(
          A + (size_t)(r0 + rr) * 32768 + k0 + kt * 64 + cc);
      *reinterpret_cast<float4*>(&At[rr * 68 + cc]) = v;
    }
    __syncthreads();
    const int rr0 = rh * 32;
    for (int kk = 0; kk < 64; kk += 4) {
      const float* bp0 = Bw + (size_t)(k0 + kt * 64 + kk) * 256 + o;
      const float* bp1 = bp0 + 128;
      float b00 = bp0[0], b01 = bp0[256], b02 = bp0[512], b03 = bp0[768];
      float b10 = bp1[0], b11 = bp1[256], b12 = bp1[512], b13 = bp1[768];
#pragma unroll
      for (int r = 0; r < 32; r++) {
        float4 a4 = *reinterpret_cast<const float4*>(&At[(rr0 + r) * 68 + kk]);
        acc0[r] += a4.x * b00 + a4.y * b01 + a4.z * b02 + a4.w * b03;
        acc1[r] += a4.x * b10 + a4.y * b11 + a4.z * b12 + a4.w * b13;
      }
    }
    __syncthreads();
  }

  float* pp = part + ((size_t)kc * 512 + r0 + rh * 32) * 256;
#pragma unroll
  for (int r = 0; r < 32; r++) {
    pp[(size_t)r * 256 + o] = acc0[r];
    pp[(size_t)r * 256 + o + 128] = acc1[r];
  }
}

// ---------------- kernel D: reduce partials + bias/relu + MLP2 + output ----------------
__global__ __launch_bounds__(256) void k_mlp2(
    const float* __restrict__ part, const float* __restrict__ b0,
    const float* __restrict__ w1, const float* __restrict__ b1,
    const float* __restrict__ ow, const float* __restrict__ ob,
    float* __restrict__ y)
{
  const int b = blockIdx.x;        // 0..511
  const int t = threadIdx.x;       // col
  __shared__ float z1[MH];
  __shared__ float red[4];

  float s = b0[t];
  for (int kc = 0; kc < 32; kc++)
    s += part[((size_t)kc * 512 + b) * 256 + t];
  z1[t] = fmaxf(s, 0.f);
  __syncthreads();

  float s2 = b1[t];
  for (int k = 0; k < 256; k += 4) {
    float4 z4 = *reinterpret_cast<const float4*>(&z1[k]);
    s2 += z4.x * w1[(k + 0) * 256 + t] + z4.y * w1[(k + 1) * 256 + t]
        + z4.z * w1[(k + 2) * 256 + t] + z4.w * w1[(k + 3) * 256 + t];
  }
  s2 = fmaxf(s2, 0.f);

  float p = s2 * ow[t];
#pragma unroll
  for (int d = 1; d < 64; d <<= 1) p += __shfl_xor(p, d);
  if ((t & 63) == 0) red[t >> 6] = p;
  __syncthreads();
  if (t == 0) y[b] = red[0] + red[1] + red[2] + red[3] + ob[0];
}

extern "C" void kernel_launch(void* const* d_in, const int* in_sizes, int n_in,
                              void* d_out, int out_size, void* d_ws, size_t ws_size,
                              hipStream_t stream) {
  const int*   ids  = (const int*)  d_in[0];
  const float* vals = (const float*)d_in[1];
  const float* adj  = (const float*)d_in[2];
  const float* emb  = (const float*)d_in[3];
  const float* W0   = (const float*)d_in[4];
  const float* a0   = (const float*)d_in[5];
  const float* W1   = (const float*)d_in[6];
  const float* a1   = (const float*)d_in[7];
  const float* mw0  = (const float*)d_in[8];
  const float* mb0  = (const float*)d_in[9];
  const float* mw1  = (const float*)d_in[10];
  const float* mb1  = (const float*)d_in[11];
  const float* ow   = (const float*)d_in[12];
  const float* ob   = (const float*)d_in[13];
  float* out = (float*)d_out;

  float* ws = (float*)d_ws;
  float* x    = ws;               // 512*128*64           = 4,194,304 floats
  float* h1   = ws + 4194304;     // 512*128*256          = 16,777,216 floats
  float* h2   = h1 + 16777216;    // 512*128*256          = 16,777,216 floats
  float* part = x;                // 32*512*256 = 4,194,304 floats — overlays dead x

  k_embed<<<4096, 256, 0, stream>>>(ids, vals, emb, x);
  k_gat<NEMB><<<BATCH * H, 256, 0, stream>>>(x, W0, a0, adj, h1);
  k_gat<NIN2><<<BATCH * H, 256, 0, stream>>>(h1, W1, a1, adj, h2);
  k_mlp1<<<dim3(32, 8), 256, 0, stream>>>(h2, mw0, part);
  k_mlp2<<<BATCH, 256, 0, stream>>>(part, mb0, mw1, mb1, ow, ob, out);
}

// Round 3
// 926.830 us; speedup vs baseline: 19.0480x; 19.0480x over previous
//
#include <hip/hip_runtime.h>
#include <math.h>

static constexpr int BATCH = 512;
static constexpr int F = 128;
static constexpr int NEMB = 64;
static constexpr int H = 8;
static constexpr int GH = 32;         // per-head hidden
static constexpr int NIN2 = H * GH;   // 256
static constexpr int MH = 256;        // MLP hidden
static constexpr float ALPHA = 0.2f;
static constexpr float NEGV = -9e15f;

// ---------------- kernel A: x[b][f][:] = emb[ids[b][f]] * vals[b][f] ----------------
__global__ __launch_bounds__(256) void k_embed(
    const int* __restrict__ ids, const float* __restrict__ vals,
    const float* __restrict__ emb, float* __restrict__ x)
{
  int idx = blockIdx.x * 256 + threadIdx.x;       // float4 index; total B*F*16
  int e4 = idx & 15;
  int bf = idx >> 4;
  int id = ids[bf];
  float v = vals[bf];
  float4 r = reinterpret_cast<const float4*>(emb)[(size_t)id * 16 + e4];
  r.x *= v; r.y *= v; r.z *= v; r.w *= v;
  reinterpret_cast<float4*>(x)[idx] = r;
}

// ---------------- kernel B: one GAT layer, one block per (b, head) ----------------
// Phase 2 design: scores live in LDS (column-major P), softmax via quad shuffles +
// in-place exp, PV is an LDS GEMM with a 2x4 register tile per thread. No per-thread
// score arrays -> no scratch spill (R1: 21 GB HBM churn per dispatch from spills).

// LDS layout (floats):
//   [0, 8704)            region R: phase1 Wl[NIN*GH], phase2 P[j=0..127][68] (col-major)
//   [8704, 8704+4608)    hW[128][36]   (row f, stride 36 keeps b128 reads conflict-free)
//   then sil[128], sjl[128], invl[64], al[64]
static constexpr int SM_R   = 0;
static constexpr int SM_HW  = 8704;
static constexpr int SM_SI  = SM_HW + 128 * 36;
static constexpr int SM_SJ  = SM_SI + 128;
static constexpr int SM_INV = SM_SJ + 128;
static constexpr int SM_AL  = SM_INV + 64;
static constexpr int SM_TOT = SM_AL + 64;   // 13,696 floats = 54,784 B -> 2 blocks/CU

template <int NIN>
__global__ __launch_bounds__(256, 2) void k_gat(
    const float* __restrict__ hin,
    const float* __restrict__ Wg,    // [H][NIN][GH]
    const float* __restrict__ ag,    // [H][2*GH]
    const float* __restrict__ adj,   // [F][F]
    float* __restrict__ hout)        // [B][F][NIN2]
{
  const int b = blockIdx.x >> 3;
  const int h = blockIdx.x & 7;
  const int t = threadIdx.x;

  __shared__ float sm[SM_TOT];
  float* Wl   = sm + SM_R;
  float* P    = sm + SM_R;     // overlays Wl after phase 1
  float* hW   = sm + SM_HW;
  float* sil  = sm + SM_SI;
  float* sjl  = sm + SM_SJ;
  float* invl = sm + SM_INV;
  float* al   = sm + SM_AL;

  {
    const float4* src = reinterpret_cast<const float4*>(Wg + (size_t)h * NIN * GH);
    float4* dst = reinterpret_cast<float4*>(Wl);
    for (int i = t; i < NIN * GH / 4; i += 256) dst[i] = src[i];
    if (t < 2 * GH) al[t] = ag[h * 2 * GH + t];
  }
  __syncthreads();

  // ---- phase 1: hW[f][o] = sum_i hin[b][f][i] * Wl[i][o]  (4 rows x 4 cols / thread)
  {
    const int fg = t >> 3;             // 0..31
    const int og = t & 7;              // 0..7
    const int f0 = fg * 4;
    float acc[4][4];
#pragma unroll
    for (int r = 0; r < 4; r++)
#pragma unroll
      for (int c = 0; c < 4; c++) acc[r][c] = 0.f;

    const float* hb = hin + ((size_t)b * F + f0) * NIN;
    for (int i = 0; i < NIN; i += 4) {
      float4 hv0 = *reinterpret_cast<const float4*>(hb + 0 * NIN + i);
      float4 hv1 = *reinterpret_cast<const float4*>(hb + 1 * NIN + i);
      float4 hv2 = *reinterpret_cast<const float4*>(hb + 2 * NIN + i);
      float4 hv3 = *reinterpret_cast<const float4*>(hb + 3 * NIN + i);
      float hs[4][4];
      hs[0][0] = hv0.x; hs[0][1] = hv0.y; hs[0][2] = hv0.z; hs[0][3] = hv0.w;
      hs[1][0] = hv1.x; hs[1][1] = hv1.y; hs[1][2] = hv1.z; hs[1][3] = hv1.w;
      hs[2][0] = hv2.x; hs[2][1] = hv2.y; hs[2][2] = hv2.z; hs[2][3] = hv2.w;
      hs[3][0] = hv3.x; hs[3][1] = hv3.y; hs[3][2] = hv3.z; hs[3][3] = hv3.w;
#pragma unroll
      for (int d = 0; d < 4; d++) {
        float4 wv = reinterpret_cast<const float4*>(Wl)[(i + d) * (GH / 4) + og];
#pragma unroll
        for (int r = 0; r < 4; r++) {
          acc[r][0] += hs[r][d] * wv.x;
          acc[r][1] += hs[r][d] * wv.y;
          acc[r][2] += hs[r][d] * wv.z;
          acc[r][3] += hs[r][d] * wv.w;
        }
      }
    }

    // store hW tile + per-row si/sj partials (reduce over the 8 og lanes)
#pragma unroll
    for (int r = 0; r < 4; r++) {
      *reinterpret_cast<float4*>(&hW[(f0 + r) * 36 + og * 4]) =
          make_float4(acc[r][0], acc[r][1], acc[r][2], acc[r][3]);
      float sip = acc[r][0] * al[og * 4 + 0] + acc[r][1] * al[og * 4 + 1]
                + acc[r][2] * al[og * 4 + 2] + acc[r][3] * al[og * 4 + 3];
      float sjp = acc[r][0] * al[GH + og * 4 + 0] + acc[r][1] * al[GH + og * 4 + 1]
                + acc[r][2] * al[GH + og * 4 + 2] + acc[r][3] * al[GH + og * 4 + 3];
      sip += __shfl_xor(sip, 1); sip += __shfl_xor(sip, 2); sip += __shfl_xor(sip, 4);
      sjp += __shfl_xor(sjp, 1); sjp += __shfl_xor(sjp, 2); sjp += __shfl_xor(sjp, 4);
      if (og == 0) { sil[f0 + r] = sip; sjl[f0 + r] = sjp; }
    }
  }
  __syncthreads();   // phase1 done; Wl region may be overwritten by P

  // ---- phase 2: two halves of 64 rows each
  for (int rh = 0; rh < 2; rh++) {
    // score pass: 4 threads per row, thread covers j = 4*jj + l
    {
      const int il = t >> 2;           // 0..63 local row
      const int i  = rh * 64 + il;
      const int l  = t & 3;
      const float si = sil[i];

      float mx = -INFINITY;
#pragma unroll
      for (int jj = 0; jj < 32; jj++) {
        int j = jj * 4 + l;
        float e = si + sjl[j];
        e = e > 0.f ? e : ALPHA * e;
        float m = adj[i * F + j];
        m = m > 0.f ? m : NEGV;
        float s = e * m;
        P[j * 68 + il] = s;            // same thread re-reads its own entries below
        mx = fmaxf(mx, s);
      }
      mx = fmaxf(mx, __shfl_xor(mx, 1));
      mx = fmaxf(mx, __shfl_xor(mx, 2));

      float sum = 0.f;
#pragma unroll
      for (int jj = 0; jj < 32; jj++) {
        int j = jj * 4 + l;
        float p = __expf(P[j * 68 + il] - mx);
        P[j * 68 + il] = p;            // unnormalized; 1/sum folded into epilogue
        sum += p;
      }
      sum += __shfl_xor(sum, 1);
      sum += __shfl_xor(sum, 2);
      if (l == 0) invl[il] = 1.f / sum;
    }
    __syncthreads();

    // PV GEMM: C[64][32] = P(col-major)[j][il] @ hW[j][o]; 2 rows x 4 cols / thread
    {
      const int rr = t >> 3;           // 0..31 -> local rows rr*2, rr*2+1
      const int og = t & 7;            // cols og*4 .. og*4+3
      float c0[4] = {0.f, 0.f, 0.f, 0.f};
      float c1[4] = {0.f, 0.f, 0.f, 0.f};
      const float* hWo = hW + og * 4;
      const float* Pr = P + rr * 2;
#pragma unroll 4
      for (int j = 0; j < 128; j++) {
        float2 pv = *reinterpret_cast<const float2*>(&Pr[j * 68]);
        float4 w  = *reinterpret_cast<const float4*>(&hWo[j * 36]);
        c0[0] += pv.x * w.x; c0[1] += pv.x * w.y; c0[2] += pv.x * w.z; c0[3] += pv.x * w.w;
        c1[0] += pv.y * w.x; c1[1] += pv.y * w.y; c1[2] += pv.y * w.z; c1[3] += pv.y * w.w;
      }
      const float inv0 = invl[rr * 2];
      const float inv1 = invl[rr * 2 + 1];
      float* pout = hout + ((size_t)b * F + rh * 64 + rr * 2) * NIN2 + h * GH + og * 4;
      float4 v0, v1;
      float* a4 = &v0.x;
      float* b4 = &v1.x;
#pragma unroll
      for (int c = 0; c < 4; c++) {
        float xA = c0[c] * inv0; a4[c] = xA > 0.f ? xA : expm1f(xA);
        float xB = c1[c] * inv1; b4[c] = xB > 0.f ? xB : expm1f(xB);
      }
      *reinterpret_cast<float4*>(pout) = v0;
      *reinterpret_cast<float4*>(pout + NIN2) = v1;
    }
    __syncthreads();   // protect P/invl before next half overwrites
  }
}

// ---------------- kernel C: MLP layer 1, K-split partial GEMM ----------------
// A = h2 [512][32768], Bw = w0 [32768][256]; part[kc][512][256] partial sums
__global__ __launch_bounds__(256, 4) void k_mlp1(
    const float* __restrict__ A, const float* __restrict__ Bw,
    float* __restrict__ part)
{
  const int kc = blockIdx.x;       // 0..31  (K chunk of 1024)
  const int rt = blockIdx.y;       // 0..7   (row tile of 64)
  const int t = threadIdx.x;
  __shared__ float At[64 * 68];

  const int r0 = rt * 64;
  const int k0 = kc * 1024;
  const int o = t & 127;           // cols {o, o+128}
  const int rh = t >> 7;           // row half (32 rows)

  float acc0[32], acc1[32];
#pragma unroll
  for (int r = 0; r < 32; r++) { acc0[r] = 0.f; acc1[r] = 0.f; }

  for (int kt = 0; kt < 16; kt++) {
#pragma unroll
    for (int it = 0; it < 4; it++) {
      int f4 = it * 256 + t;                 // 0..1023
      int rr = f4 >> 4;
      int cc = (f4 & 15) * 4;
      float4 v = *reinterpret_cast<const float4*>(
          A + (size_t)(r0 + rr) * 32768 + k0 + kt * 64 + cc);
      *reinterpret_cast<float4*>(&At[rr * 68 + cc]) = v;
    }
    __syncthreads();
    const int rr0 = rh * 32;
    for (int kk = 0; kk < 64; kk += 4) {
      const float* bp0 = Bw + (size_t)(k0 + kt * 64 + kk) * 256 + o;
      const float* bp1 = bp0 + 128;
      float b00 = bp0[0], b01 = bp0[256], b02 = bp0[512], b03 = bp0[768];
      float b10 = bp1[0], b11 = bp1[256], b12 = bp1[512], b13 = bp1[768];
#pragma unroll
      for (int r = 0; r < 32; r++) {
        float4 a4 = *reinterpret_cast<const float4*>(&At[(rr0 + r) * 68 + kk]);
        acc0[r] += a4.x * b00 + a4.y * b01 + a4.z * b02 + a4.w * b03;
        acc1[r] += a4.x * b10 + a4.y * b11 + a4.z * b12 + a4.w * b13;
      }
    }
    __syncthreads();
  }

  float* pp = part + ((size_t)kc * 512 + r0 + rh * 32) * 256;
#pragma unroll
  for (int r = 0; r < 32; r++) {
    pp[(size_t)r * 256 + o] = acc0[r];
    pp[(size_t)r * 256 + o + 128] = acc1[r];
  }
}

// ---------------- kernel D: reduce partials + bias/relu + MLP2 + output ----------------
__global__ __launch_bounds__(256) void k_mlp2(
    const float* __restrict__ part, const float* __restrict__ b0,
    const float* __restrict__ w1, const float* __restrict__ b1,
    const float* __restrict__ ow, const float* __restrict__ ob,
    float* __restrict__ y)
{
  const int b = blockIdx.x;        // 0..511
  const int t = threadIdx.x;       // col
  __shared__ float z1[MH];
  __shared__ float red[4];

  float s = b0[t];
  for (int kc = 0; kc < 32; kc++)
    s += part[((size_t)kc * 512 + b) * 256 + t];
  z1[t] = fmaxf(s, 0.f);
  __syncthreads();

  float s2 = b1[t];
  for (int k = 0; k < 256; k += 4) {
    float4 z4 = *reinterpret_cast<const float4*>(&z1[k]);
    s2 += z4.x * w1[(k + 0) * 256 + t] + z4.y * w1[(k + 1) * 256 + t]
        + z4.z * w1[(k + 2) * 256 + t] + z4.w * w1[(k + 3) * 256 + t];
  }
  s2 = fmaxf(s2, 0.f);

  float p = s2 * ow[t];
#pragma unroll
  for (int d = 1; d < 64; d <<= 1) p += __shfl_xor(p, d);
  if ((t & 63) == 0) red[t >> 6] = p;
  __syncthreads();
  if (t == 0) y[b] = red[0] + red[1] + red[2] + red[3] + ob[0];
}

extern "C" void kernel_launch(void* const* d_in, const int* in_sizes, int n_in,
                              void* d_out, int out_size, void* d_ws, size_t ws_size,
                              hipStream_t stream) {
  const int*   ids  = (const int*)  d_in[0];
  const float* vals = (const float*)d_in[1];
  const float* adj  = (const float*)d_in[2];
  const float* emb  = (const float*)d_in[3];
  const float* W0   = (const float*)d_in[4];
  const float* a0   = (const float*)d_in[5];
  const float* W1   = (const float*)d_in[6];
  const float* a1   = (const float*)d_in[7];
  const float* mw0  = (const float*)d_in[8];
  const float* mb0  = (const float*)d_in[9];
  const float* mw1  = (const float*)d_in[10];
  const float* mb1  = (const float*)d_in[11];
  const float* ow   = (const float*)d_in[12];
  const float* ob   = (const float*)d_in[13];
  float* out = (float*)d_out;

  float* ws = (float*)d_ws;
  float* x    = ws;               // 512*128*64           = 4,194,304 floats
  float* h1   = ws + 4194304;     // 512*128*256          = 16,777,216 floats
  float* h2   = h1 + 16777216;    // 512*128*256          = 16,777,216 floats
  float* part = x;                // 32*512*256 = 4,194,304 floats — overlays dead x

  k_embed<<<4096, 256, 0, stream>>>(ids, vals, emb, x);
  k_gat<NEMB><<<BATCH * H, 256, 0, stream>>>(x, W0, a0, adj, h1);
  k_gat<NIN2><<<BATCH * H, 256, 0, stream>>>(h1, W1, a1, adj, h2);
  k_mlp1<<<dim3(32, 8), 256, 0, stream>>>(h2, mw0, part);
  k_mlp2<<<BATCH, 256, 0, stream>>>(part, mb0, mw1, mb1, ow, ob, out);
}